// Round 4
// baseline (355.896 us; speedup 1.0000x reference)
//
#include <hip/hip_runtime.h>
#include <hip/hip_bf16.h>

typedef _Float16 f16x8 __attribute__((ext_vector_type(8)));
typedef _Float16 f16x4 __attribute__((ext_vector_type(4)));
typedef float f32x4 __attribute__((ext_vector_type(4)));

#define MFMA32(a, b, c) __builtin_amdgcn_mfma_f32_16x16x32_f16(a, b, c, 0, 0, 0)
#define MFMA16(a, b, c) __builtin_amdgcn_mfma_f32_16x16x16f16(a, b, c, 0, 0, 0)

// async global->LDS, 16B per lane, linear dest (wave base + lane*16)
#define GLOAD_LDS16(g, l)                                         \
  __builtin_amdgcn_global_load_lds(                               \
      (const __attribute__((address_space(1))) void*)(g),         \
      (__attribute__((address_space(3))) void*)(l), 16, 0, 0)

// ---------------------------------------------------------------------------
// Kernel 0a: batched transpose + f32->f16 convert.
// ---------------------------------------------------------------------------
__global__ __launch_bounds__(256) void tconv_kernel(
    const float* __restrict__ in, _Float16* __restrict__ out, int R, int C) {
  size_t bat = (size_t)blockIdx.y * R * C;
  int o = blockIdx.x * 256 + threadIdx.x;
  if (o < R * C) {
    int c = o / R, r = o - c * R;
    out[bat + o] = (_Float16)in[bat + (size_t)r * C + c];
  }
}

// ---------------------------------------------------------------------------
// Kernel 0b: straight f32 -> f16 convert, 8 elts/thread.
// ---------------------------------------------------------------------------
__global__ __launch_bounds__(256) void cvt16_kernel(
    const float* __restrict__ in, _Float16* __restrict__ out, int n) {
  int i = (blockIdx.x * 256 + threadIdx.x) * 8;
  if (i < n) {
    float4 a = *(const float4*)(in + i);
    float4 b = *(const float4*)(in + i + 4);
    f16x8 cv;
    cv[0] = (_Float16)a.x; cv[1] = (_Float16)a.y;
    cv[2] = (_Float16)a.z; cv[3] = (_Float16)a.w;
    cv[4] = (_Float16)b.x; cv[5] = (_Float16)b.y;
    cv[6] = (_Float16)b.z; cv[7] = (_Float16)b.w;
    *(f16x8*)(out + i) = cv;
  }
}

// ---------------------------------------------------------------------------
// Kernel 1: fused QKV projection as ONE GEMM — 256x256 8-phase schedule.
// C[m][n] = sum_e zh[m][e] * Ut[n][e],  M=16384, N=2304, K=768.
// BM=BN=256, BK=64, 8 waves (2Mx4N), per-wave output 128x64.
// LDS 128KB: 2 dbuf x (A 256x64 + B 256x64) f16, XOR-swizzled (both-sides:
// pre-swizzled global source + swizzled ds_read; measured 0 conflicts).
// Per K-tile t: 4 phases (C-quadrants), each {12x ds_read_b128 ||
// stage-burst for tile t+1 into buf[(t+1)&1] (A at phase 0, B at phase 1)
// -> s_barrier -> setprio(1) -> 16 MFMA -> setprio(0) -> s_barrier}.
// Group start: per-wave vmcnt(0) + s_barrier (tile t's loads were issued
// >=2 phases earlier -> wait nearly satisfied; issue-early/wait-late).
// Hazards: stages for t+1 hit the buffer last read in tile t-1, released by
// t-1's final barrier; tile t's DMA proven landed by vmcnt(0)+barrier.
// ---------------------------------------------------------------------------
__global__ __launch_bounds__(512) void qkv_gemm_kernel(
    const _Float16* __restrict__ zh, const _Float16* __restrict__ Ut,
    _Float16* __restrict__ Qf, _Float16* __restrict__ Kf,
    _Float16* __restrict__ Vt) {
  __shared__ _Float16 As[2][256 * 64];
  __shared__ _Float16 Bs[2][256 * 64];

  const int tid = threadIdx.x;
  const int wid = tid >> 6, lane = tid & 63, quad = lane >> 4, l16 = lane & 15;
  const int wr = wid >> 2, wc = wid & 3;  // wave grid 2M x 4N

  const int m0 = blockIdx.x * 256;
  const int by = blockIdx.y;
  const int n0 = by * 256;

  // staging source (pre-swizzled): lane covers row srow(+8k), 16B chunk scol
  const int srow = lane >> 3;
  const int scol = ((lane & 7) ^ srow) << 3;  // f16 units
  const _Float16* Ag = zh + (size_t)(m0 + srow) * 768 + scol;
  const _Float16* Bg = Ut + (size_t)(n0 + srow) * 768 + scol;

// stage one matrix (4 x 1KB wave-slices, rows (wid*2+i)*8 and +128)
#define STAGE_A(buf, t)                                                  \
  {                                                                      \
    _Pragma("unroll") for (int hf = 0; hf < 2; ++hf)                     \
        _Pragma("unroll") for (int i = 0; i < 2; ++i) {                  \
      const int rb = hf * 128 + (wid * 2 + i) * 8;                       \
      GLOAD_LDS16(Ag + (size_t)rb * 768 + (t) * 64,                      \
                  (char*)&As[buf][0] + rb * 128);                        \
    }                                                                    \
  }
#define STAGE_B(buf, t)                                                  \
  {                                                                      \
    _Pragma("unroll") for (int hf = 0; hf < 2; ++hf)                     \
        _Pragma("unroll") for (int i = 0; i < 2; ++i) {                  \
      const int rb = hf * 128 + (wid * 2 + i) * 8;                       \
      GLOAD_LDS16(Bg + (size_t)rb * 768 + (t) * 64,                      \
                  (char*)&Bs[buf][0] + rb * 128);                        \
    }                                                                    \
  }

  f32x4 acc[8][4] = {};

  // prologue: stage K-tile 0 into buffer 0 (8 loads/wave)
  STAGE_A(0, 0);
  STAGE_B(0, 0);

  for (int t = 0; t < 12; ++t) {
    const int cur = t & 1;
    // this tile's DMA must have landed (per-wave wait, then align all waves)
    asm volatile("s_waitcnt vmcnt(0)" ::: "memory");
    asm volatile("s_barrier" ::: "memory");
#pragma unroll
    for (int q = 0; q < 4; ++q) {
      const int mh = q >> 1, nh = q & 1;
      f16x8 af[4][2], bf[2][2];
#pragma unroll
      for (int mf = 0; mf < 4; ++mf) {
        const int r = wr * 128 + mh * 64 + mf * 16 + l16;
#pragma unroll
        for (int ks = 0; ks < 2; ++ks)
          af[mf][ks] =
              *(const f16x8*)((const char*)&As[cur][0] + r * 128 +
                              ((ks * 64 + quad * 16) ^ ((r & 7) << 4)));
      }
#pragma unroll
      for (int j = 0; j < 2; ++j) {
        const int r = wc * 64 + nh * 32 + j * 16 + l16;
#pragma unroll
        for (int ks = 0; ks < 2; ++ks)
          bf[j][ks] =
              *(const f16x8*)((const char*)&Bs[cur][0] + r * 128 +
                              ((ks * 64 + quad * 16) ^ ((r & 7) << 4)));
      }
      // stage burst for tile t+1 (other buffer): A at phase 0, B at phase 1
      if (t < 11) {
        if (q == 0) STAGE_A(cur ^ 1, t + 1)
        else if (q == 1) STAGE_B(cur ^ 1, t + 1)
      }
      asm volatile("s_barrier" ::: "memory");
      __builtin_amdgcn_s_setprio(1);
#pragma unroll
      for (int mf = 0; mf < 4; ++mf)
#pragma unroll
        for (int j = 0; j < 2; ++j)
#pragma unroll
          for (int ks = 0; ks < 2; ++ks)
            acc[mh * 4 + mf][nh * 2 + j] =
                MFMA32(af[mf][ks], bf[j][ks], acc[mh * 4 + mf][nh * 2 + j]);
      __builtin_amdgcn_s_setprio(0);
      asm volatile("s_barrier" ::: "memory");
    }
  }

  // epilogue: scatter to Q, K [h,b,n,d] and V^T [h,b,d,n]
  const int g = by * 4 + wc;
  const int hd = g / 3, kk = g - hd * 3;
#pragma unroll
  for (int mfp = 0; mfp < 8; ++mfp) {
#pragma unroll
    for (int nfp = 0; nfp < 4; ++nfp) {
      const int dd = nfp * 16 + l16;
#pragma unroll
      for (int r = 0; r < 4; ++r) {
        int m = m0 + wr * 128 + mfp * 16 + quad * 4 + r;
        int b = m >> 10, n = m & 1023;
        _Float16 val = (_Float16)acc[mfp][nfp][r];
        if (kk == 0)
          Qf[(((size_t)hd * 16 + b) * 1024 + n) * 64 + dd] = val;
        else if (kk == 1)
          Kf[(((size_t)hd * 16 + b) * 1024 + n) * 64 + dd] = val;
        else
          Vt[(((size_t)hd * 16 + b) * 64 + dd) * 1024 + n] = val;
      }
    }
  }
#undef STAGE_A
#undef STAGE_B
}

// ---------------------------------------------------------------------------
// Kernel 2: flash attention per (h,b).  (unchanged from R2: dbuf K/V LDS,
// one barrier/tile, setprio on MFMA clusters, XCD-chunked grid, nt-stores.)
// ---------------------------------------------------------------------------
__global__ __launch_bounds__(256) void attn_kernel(
    const _Float16* __restrict__ Qf, const _Float16* __restrict__ Kf,
    const _Float16* __restrict__ Vt, _Float16* __restrict__ Of) {
  __shared__ _Float16 Ks[2][64][72];
  __shared__ _Float16 Vs[2][64][72];

  const int tid = threadIdx.x;
  const int wv = tid >> 6, lane = tid & 63, quad = lane >> 4, l16 = lane & 15;

  const int flat = blockIdx.x;
  const int swz = (flat & 7) * 192 + (flat >> 3);
  const int hb = swz >> 3;
  const int h = hb >> 4, b = hb & 15;
  const _Float16* Q = Qf + (size_t)hb * 65536;
  const _Float16* K = Kf + (size_t)hb * 65536;
  const _Float16* V = Vt + (size_t)hb * 65536;  // [64 dd][1024 n]
  const int q0 = (swz & 7) * 128 + wv * 32;

  const _Float16 cs = (_Float16)0.18033688011112042f;
  f16x8 qfr[2][2];
#pragma unroll
  for (int mi = 0; mi < 2; ++mi) {
    const _Float16* qp = Q + (size_t)(q0 + mi * 16 + l16) * 64 + quad * 8;
    qfr[mi][0] = *(const f16x8*)qp * cs;
    qfr[mi][1] = *(const f16x8*)(qp + 32) * cs;
  }

  const int r0 = tid >> 3, c0 = (tid & 7) << 3;
  const _Float16* Kst = K + (size_t)r0 * 64 + c0;
  const _Float16* Vst = V + (size_t)r0 * 1024 + c0;

  uint4 kreg[2], vreg[2];
#pragma unroll
  for (int i = 0; i < 2; ++i) {
    kreg[i] = *(const uint4*)(Kst + i * 2048);
    vreg[i] = *(const uint4*)(Vst + i * 32768);
  }
#pragma unroll
  for (int i = 0; i < 2; ++i) {
    *(uint4*)&Ks[0][r0 + i * 32][c0] = kreg[i];
    *(uint4*)&Vs[0][r0 + i * 32][c0] = vreg[i];
  }
  __syncthreads();

  f32x4 o[2][4] = {};
  float lsum[2] = {};

  for (int t = 0; t < 16; ++t) {
    const int cur = t & 1;
    if (t < 15) {
      int n1 = (t + 1) * 64;
#pragma unroll
      for (int i = 0; i < 2; ++i) {
        kreg[i] = *(const uint4*)(Kst + (size_t)n1 * 64 + i * 2048);
        vreg[i] = *(const uint4*)(Vst + n1 + i * 32768);
      }
    }

    f32x4 st[2][4] = {};
    __builtin_amdgcn_s_setprio(1);
#pragma unroll
    for (int ct = 0; ct < 4; ++ct) {
      f16x8 kf0 = *(const f16x8*)&Ks[cur][ct * 16 + l16][quad * 8];
      f16x8 kf1 = *(const f16x8*)&Ks[cur][ct * 16 + l16][32 + quad * 8];
#pragma unroll
      for (int mi = 0; mi < 2; ++mi) {
        st[mi][ct] = MFMA32(kf0, qfr[mi][0], st[mi][ct]);
        st[mi][ct] = MFMA32(kf1, qfr[mi][1], st[mi][ct]);
      }
    }
    __builtin_amdgcn_s_setprio(0);

    f16x4 pa[2][4];
#pragma unroll
    for (int mi = 0; mi < 2; ++mi)
#pragma unroll
      for (int ct = 0; ct < 4; ++ct)
#pragma unroll
        for (int r = 0; r < 4; ++r) {
          float p = __builtin_amdgcn_exp2f(st[mi][ct][r]);
          lsum[mi] += p;
          pa[mi][ct][r] = (_Float16)p;
        }

    __builtin_amdgcn_s_setprio(1);
#pragma unroll
    for (int dt = 0; dt < 4; ++dt) {
#pragma unroll
      for (int kb = 0; kb < 4; ++kb) {
        f16x4 vf = *(const f16x4*)&Vs[cur][dt * 16 + l16][kb * 16 + quad * 4];
#pragma unroll
        for (int mi = 0; mi < 2; ++mi)
          o[mi][dt] = MFMA16(pa[mi][kb], vf, o[mi][dt]);
      }
    }
    __builtin_amdgcn_s_setprio(0);

    if (t < 15) {
#pragma unroll
      for (int i = 0; i < 2; ++i) {
        *(uint4*)&Ks[cur ^ 1][r0 + i * 32][c0] = kreg[i];
        *(uint4*)&Vs[cur ^ 1][r0 + i * 32][c0] = vreg[i];
      }
      __syncthreads();
    }
  }

#pragma unroll
  for (int mi = 0; mi < 2; ++mi) {
    float s = lsum[mi];
    s += __shfl_xor(s, 16, 64);
    s += __shfl_xor(s, 32, 64);
    lsum[mi] = s;
  }

#pragma unroll
  for (int mi = 0; mi < 2; ++mi) {
#pragma unroll
    for (int r = 0; r < 4; ++r) {
      float inv = 1.f / __shfl(lsum[mi], quad * 4 + r, 64);
      int n = q0 + mi * 16 + quad * 4 + r;
#pragma unroll
      for (int dt = 0; dt < 4; ++dt) {
        int dd = dt * 16 + l16;
        __builtin_nontemporal_store(
            (_Float16)(o[mi][dt][r] * inv),
            &Of[((size_t)b * 1024 + n) * 768 + h * 64 + dd]);
      }
    }
  }
}

// ---------------------------------------------------------------------------
// Kernel 3: output projection.  C[m][n] = sum_k Of[m][k] * U_msa[k][n].
// Counted-wait double-buffered 2-phase (improved ~28us in R3 — keep).
// ---------------------------------------------------------------------------
__global__ __launch_bounds__(256) void out_gemm_kernel(
    const _Float16* __restrict__ A, const _Float16* __restrict__ Bt,
    float* __restrict__ Cout) {
  __shared__ _Float16 As[2][128 * 64];
  __shared__ _Float16 Bs[2][128 * 64];

  const int tid = threadIdx.x;
  const int wv = tid >> 6, lane = tid & 63, quad = lane >> 4, l16 = lane & 15;

  const int m0 = blockIdx.x * 128;
  const int n0 = blockIdx.y * 128;

  const int srow = lane >> 3;
  const int scol = ((lane & 7) ^ srow) << 3;
  const _Float16* Ag = A + (size_t)(m0 + srow) * 768 + scol;
  const _Float16* Bg = Bt + (size_t)(n0 + srow) * 768 + scol;

  const int cbq = quad * 16;

  f32x4 acc[2][8] = {};

#pragma unroll
  for (int i = 0; i < 4; ++i) {
    const int rb = (i * 4 + wv) * 8;
    GLOAD_LDS16(Ag + (size_t)rb * 768, (char*)As[0] + rb * 128);
    GLOAD_LDS16(Bg + (size_t)rb * 768, (char*)Bs[0] + rb * 128);
  }
  asm volatile("s_waitcnt vmcnt(0)" ::: "memory");
  __builtin_amdgcn_s_barrier();

  for (int t = 0; t < 12; ++t) {
    const int cur = t & 1;
    if (t < 11) {
      const int k1 = (t + 1) * 64;
#pragma unroll
      for (int i = 0; i < 4; ++i) {
        const int rb = (i * 4 + wv) * 8;
        GLOAD_LDS16(Ag + (size_t)rb * 768 + k1,
                    (char*)As[cur ^ 1] + rb * 128);
        GLOAD_LDS16(Bg + (size_t)rb * 768 + k1,
                    (char*)Bs[cur ^ 1] + rb * 128);
      }
    }
#pragma unroll
    for (int ks = 0; ks < 2; ++ks) {
      f16x8 af[2], bfr[8];
#pragma unroll
      for (int rt = 0; rt < 2; ++rt) {
        const int r = wv * 32 + rt * 16 + l16;
        af[rt] = *(const f16x8*)((const char*)As[cur] + r * 128 +
                                 ((ks * 64 + cbq) ^ ((r & 7) << 4)));
      }
#pragma unroll
      for (int ct = 0; ct < 8; ++ct) {
        const int r = ct * 16 + l16;
        bfr[ct] = *(const f16x8*)((const char*)Bs[cur] + r * 128 +
                                  ((ks * 64 + cbq) ^ ((r & 7) << 4)));
      }
#pragma unroll
      for (int rt = 0; rt < 2; ++rt)
#pragma unroll
        for (int ct = 0; ct < 8; ++ct)
          acc[rt][ct] = MFMA32(af[rt], bfr[ct], acc[rt][ct]);
    }
    if (t < 11) {
      asm volatile("s_waitcnt vmcnt(0)" ::: "memory");
      __builtin_amdgcn_s_barrier();
    }
  }

#pragma unroll
  for (int rt = 0; rt < 2; ++rt) {
#pragma unroll
    for (int ct = 0; ct < 8; ++ct) {
#pragma unroll
      for (int r = 0; r < 4; ++r) {
        int m = m0 + wv * 32 + rt * 16 + quad * 4 + r;
        int n = n0 + ct * 16 + l16;
        __builtin_nontemporal_store(acc[rt][ct][r],
                                    &Cout[(size_t)m * 768 + n]);
      }
    }
  }
}

// ---------------------------------------------------------------------------
// Workspace layout (bytes), total 105,381,888:
//   Ut_qkv @ 0           36*64*768*2    =  3,538,944   ([2304][768] f16)
//   Ut_msa @ 3,538,944   768*768*2      =  1,179,648
//   zh/Of  @ 4,718,592   16384*768*2    = 25,165,824   (aliased)
//   Qf     @ 29,884,416  25,165,824
//   Kf     @ 55,050,240  25,165,824
//   Vt     @ 80,216,064  25,165,824  ([h][b][d][n])
// ---------------------------------------------------------------------------
extern "C" void kernel_launch(void* const* d_in, const int* in_sizes, int n_in,
                              void* d_out, int out_size, void* d_ws,
                              size_t ws_size, hipStream_t stream) {
  const float* z = (const float*)d_in[0];
  const float* Uqkv = (const float*)d_in[1];
  const float* Umsa = (const float*)d_in[2];

  char* ws = (char*)d_ws;
  _Float16* Ut_qkv = (_Float16*)(ws);
  _Float16* Ut_msa = (_Float16*)(ws + 3538944);
  _Float16* zh = (_Float16*)(ws + 4718592);
  _Float16* Of = zh;  // aliased (zh dead before attn writes Of)
  _Float16* Qf = (_Float16*)(ws + 29884416);
  _Float16* Kf = (_Float16*)(ws + 55050240);
  _Float16* Vt = (_Float16*)(ws + 80216064);

  tconv_kernel<<<dim3(192, 36), 256, 0, stream>>>(Uqkv, Ut_qkv, 768, 64);
  tconv_kernel<<<dim3(2304, 1), 256, 0, stream>>>(Umsa, Ut_msa, 768, 768);
  cvt16_kernel<<<dim3(6144, 1), 256, 0, stream>>>(z, zh, 16384 * 768);

  qkv_gemm_kernel<<<dim3(64, 9), 512, 0, stream>>>(zh, Ut_qkv, Qf, Kf, Vt);
  attn_kernel<<<dim3(1536, 1), 256, 0, stream>>>(Qf, Kf, Vt, Of);
  out_gemm_kernel<<<dim3(128, 6), 256, 0, stream>>>(Of, Ut_msa,
                                                    (float*)d_out);
}